// Round 4
// baseline (270.767 us; speedup 1.0000x reference)
//
#include <hip/hip_runtime.h>

typedef _Float16 f16x8 __attribute__((ext_vector_type(8)));
typedef _Float16 f16x4 __attribute__((ext_vector_type(4)));
typedef __fp16   fp16x2 __attribute__((ext_vector_type(2)));
typedef float    f32x4 __attribute__((ext_vector_type(4)));

static constexpr float kLOW  = 0.02f;
static constexpr float kHIGH = 0.98f;

__device__ __forceinline__ float fast_rcp(float v) {
    return __builtin_amdgcn_rcpf(v);  // v_rcp_f32, ~1e-7 rel err
}
__device__ __forceinline__ float fast_sigmoid(float v) {
    return fast_rcp(1.0f + __expf(-v));
}
// relu + packed f32->f16 (RTZ): 1 v_cvt_pkrtz_f16_f32 per 2 elems vs 3 insts
__device__ __forceinline__ unsigned int relu_pk(float a, float b) {
    fp16x2 r = __builtin_amdgcn_cvt_pkrtz(fmaxf(a, 0.0f), fmaxf(b, 0.0f));
    return __builtin_bit_cast(unsigned int, r);
}

// ---------------- workspace layout (bytes) ----------------
enum : int {
    WS_A1 = 0,        // [4 mt][64 lane] f16x8   W1^T frags (K=32 pad, q>0 zero)
    WS_A2 = 4096,     // [2 mt][2 kt][64] f16x8  W2^T frags
    WS_A3 = 8192,     // [64] f16x8              W3^T frag
    WS_A4 = 9216,     // [64] f16x8              W4^T frag (M=16 pad, K=32 pad)
    WS_B1 = 10240,    // [4 mt][64] f32x4        b1 per-lane C-in rows
    WS_B2 = 14336,    // [2 mt][64] f32x4
    WS_B3 = 16384,    // [64] f32x4
    WS_B4 = 17408,    // [64] f32x4 (rows >=9 zeroed)
    WS_TOTAL = 18432
};

__global__ __launch_bounds__(256) void prep_frags(
    const float* __restrict__ W1, const float* __restrict__ b1,
    const float* __restrict__ W2, const float* __restrict__ b2,
    const float* __restrict__ W3, const float* __restrict__ b3,
    const float* __restrict__ W4, const float* __restrict__ b4,
    char* __restrict__ ws)
{
    const int lane = threadIdx.x & 63;
    const int wid  = threadIdx.x >> 6;
    const int n16  = lane & 15;
    const int q    = lane >> 4;

    if (wid == 0) {
#pragma unroll
        for (int mt = 0; mt < 4; ++mt) {
            f16x8 a;
#pragma unroll
            for (int j = 0; j < 8; ++j) a[j] = (_Float16)0.0f;
            if (q == 0) {
#pragma unroll
                for (int j = 0; j < 6; ++j)
                    a[j] = (_Float16)W1[j * 64 + mt * 16 + n16];
            }
            ((f16x8*)(ws + WS_A1))[mt * 64 + lane] = a;
        }
#pragma unroll
        for (int mt = 0; mt < 4; ++mt)
            ((f32x4*)(ws + WS_B1))[mt * 64 + lane] = *(const f32x4*)(b1 + mt * 16 + q * 4);
    } else if (wid == 1) {
#pragma unroll
        for (int mt = 0; mt < 2; ++mt)
#pragma unroll
            for (int kt = 0; kt < 2; ++kt) {
                f16x8 a;
#pragma unroll
                for (int j = 0; j < 8; ++j)
                    a[j] = (_Float16)W2[(kt * 32 + q * 8 + j) * 32 + mt * 16 + n16];
                ((f16x8*)(ws + WS_A2))[(mt * 2 + kt) * 64 + lane] = a;
            }
    } else if (wid == 2) {
        f16x8 a3;
#pragma unroll
        for (int j = 0; j < 8; ++j)
            a3[j] = (_Float16)W3[(q * 8 + j) * 16 + n16];
        ((f16x8*)(ws + WS_A3))[lane] = a3;
        f16x8 a4;
#pragma unroll
        for (int j = 0; j < 8; ++j) {
            const int k = q * 8 + j;
            a4[j] = (k < 16 && n16 < 9) ? (_Float16)W4[k * 9 + n16] : (_Float16)0.0f;
        }
        ((f16x8*)(ws + WS_A4))[lane] = a4;
    } else {
#pragma unroll
        for (int mt = 0; mt < 2; ++mt)
            ((f32x4*)(ws + WS_B2))[mt * 64 + lane] = *(const f32x4*)(b2 + mt * 16 + q * 4);
        ((f32x4*)(ws + WS_B3))[lane] = *(const f32x4*)(b3 + q * 4);
        f32x4 bb;
#pragma unroll
        for (int r = 0; r < 4; ++r) {
            const int m = q * 4 + r;
            bb[r] = (m < 9) ? b4[m] : 0.0f;
        }
        ((f32x4*)(ws + WS_B4))[lane] = bb;
    }
}

// Per-wave LDS slice 8192 B (was 9216: unpadded h1 + XOR swizzle + x overlay
// -> 5 blocks/CU instead of 4, LDS = 5*32768 = exactly 160 KiB).
// Regions (time-multiplexed; every hazard is read-to-regs-before-overwrite
// within the same wave, ordered by the compiler's lgkmcnt):
//   x^T f16 rows @ 7168..8192 (aliases h1 rows 56..63; x is fully consumed
//     into BX registers before any h1 write)
//   h1 f16 [b][128 B] swizzled (byte ^= (b&7)<<4) @ 0..8192
//   h2 f16 [b][32] stride  80 @ 0..5104
//   h3 f16 [b][16] stride  32 @ 0..2048
//   pbuf f32 [b][12+pad] stride 80 @ 2560..7664
__global__ __launch_bounds__(256, 5) void sinkhorn_mlp_mfma(
    const float* __restrict__ margins, const char* __restrict__ ws,
    float* __restrict__ out_mus, float* __restrict__ out_V, int B)
{
    __shared__ __align__(16) char smem_all[4 * 8192];
    const int lane = threadIdx.x & 63;
    const int wid  = threadIdx.x >> 6;
    char* smem = smem_all + wid * 8192;

    const int n16 = lane & 15;   // MFMA tile row/col index
    const int q   = lane >> 4;   // quad 0..3

    const int row  = blockIdx.x * 256 + wid * 64 + lane;
    const int rowC = row < B ? row : (B - 1);

    // ---- load input row (f32 kept for sinkhorn margins) ----
    float x[6];
    {
        const float2* mp = (const float2*)(margins + (size_t)rowC * 6);
        const float2 a = mp[0], b = mp[1], c = mp[2];
        x[0] = a.x; x[1] = a.y; x[2] = b.x; x[3] = b.y; x[4] = c.x; x[5] = c.y;
    }

    // ---- stage x^T rows as f16 (k=0..5 data, 6..7 zero) ----
    {
        f16x8 xr;
#pragma unroll
        for (int j = 0; j < 8; ++j) xr[j] = (_Float16)0.0f;
#pragma unroll
        for (int i = 0; i < 6; ++i) xr[i] = (_Float16)x[i];
        *(f16x8*)(smem + 7168 + lane * 16) = xr;
    }

    // ---- fragments: coalesced b128 loads from prepacked ws ----
    f16x8 A1[4], A2w[2][2], A3w, A4w;
#pragma unroll
    for (int mt = 0; mt < 4; ++mt) A1[mt] = ((const f16x8*)(ws + WS_A1))[mt * 64 + lane];
#pragma unroll
    for (int mt = 0; mt < 2; ++mt)
#pragma unroll
        for (int kt = 0; kt < 2; ++kt)
            A2w[mt][kt] = ((const f16x8*)(ws + WS_A2))[(mt * 2 + kt) * 64 + lane];
    A3w = ((const f16x8*)(ws + WS_A3))[lane];
    A4w = ((const f16x8*)(ws + WS_A4))[lane];

    f32x4 b1v[4], b2v[2], b3v, b4v;
#pragma unroll
    for (int mt = 0; mt < 4; ++mt) b1v[mt] = ((const f32x4*)(ws + WS_B1))[mt * 64 + lane];
#pragma unroll
    for (int mt = 0; mt < 2; ++mt) b2v[mt] = ((const f32x4*)(ws + WS_B2))[mt * 64 + lane];
    b3v = ((const f32x4*)(ws + WS_B3))[lane];
    b4v = ((const f32x4*)(ws + WS_B4))[lane];

    // ---- layer 1: h1^T = W1^T x^T  (M=64, N=64, K=32 pad) ----
    // B-frag rows k=8..31 are zero: q>0 lanes take register zeros (no LDS).
    f16x8 BX[4];
    if (q == 0) {
#pragma unroll
        for (int nt = 0; nt < 4; ++nt)
            BX[nt] = *(const f16x8*)(smem + 7168 + (nt * 16 + n16) * 16);
    } else {
#pragma unroll
        for (int nt = 0; nt < 4; ++nt)
#pragma unroll
            for (int j = 0; j < 8; ++j) BX[nt][j] = (_Float16)0.0f;
    }
#pragma unroll
    for (int mt = 0; mt < 4; ++mt) {
#pragma unroll
        for (int nt = 0; nt < 4; ++nt) {
            f32x4 C = b1v[mt];
            C = __builtin_amdgcn_mfma_f32_16x16x32_f16(A1[mt], BX[nt], C, 0, 0, 0);
            uint2 hv;
            hv.x = relu_pk(C[0], C[1]);
            hv.y = relu_pk(C[2], C[3]);
            const int r = nt * 16 + n16;                       // batch row
            const int col = (mt * 32 + q * 8) ^ ((r & 7) << 4); // XOR swizzle
            *(uint2*)(smem + r * 128 + col) = hv;
        }
    }

    // ---- layer 2: h2^T = W2^T h1^T  (M=32, N=64, K=64) ----
    f16x8 H1f[4][2];
#pragma unroll
    for (int nt = 0; nt < 4; ++nt) {
        const int r = nt * 16 + n16;
#pragma unroll
        for (int kt = 0; kt < 2; ++kt) {
            const int col = (kt * 64 + q * 16) ^ ((r & 7) << 4);
            H1f[nt][kt] = *(const f16x8*)(smem + r * 128 + col);
        }
    }
#pragma unroll
    for (int mt = 0; mt < 2; ++mt) {
#pragma unroll
        for (int nt = 0; nt < 4; ++nt) {
            f32x4 C = b2v[mt];
            C = __builtin_amdgcn_mfma_f32_16x16x32_f16(A2w[mt][0], H1f[nt][0], C, 0, 0, 0);
            C = __builtin_amdgcn_mfma_f32_16x16x32_f16(A2w[mt][1], H1f[nt][1], C, 0, 0, 0);
            uint2 hv;
            hv.x = relu_pk(C[0], C[1]);
            hv.y = relu_pk(C[2], C[3]);
            *(uint2*)(smem + (nt*16 + n16) * 80 + mt*32 + q*8) = hv;
        }
    }

    // ---- layer 3: h3^T = W3^T h2^T  (M=16, N=64, K=32), RNE for accuracy ----
    f16x8 H2f[4];
#pragma unroll
    for (int nt = 0; nt < 4; ++nt)
        H2f[nt] = *(const f16x8*)(smem + (nt*16 + n16) * 80 + q*16);
#pragma unroll
    for (int nt = 0; nt < 4; ++nt) {
        f32x4 C = b3v;
        C = __builtin_amdgcn_mfma_f32_16x16x32_f16(A3w, H2f[nt], C, 0, 0, 0);
        f16x4 hv;
#pragma unroll
        for (int r = 0; r < 4; ++r) hv[r] = (_Float16)fmaxf(C[r], 0.0f);
        *(f16x4*)(smem + (nt*16 + n16) * 32 + q*8) = hv;
    }

    // ---- layer 4 on MFMA: p^T = W4^T h3^T (M=16 pad(9), N=64, K=32 pad(16)) ----
    f16x8 B4[4];
    if (q < 2) {
#pragma unroll
        for (int nt = 0; nt < 4; ++nt)
            B4[nt] = *(const f16x8*)(smem + (nt*16 + n16) * 32 + q * 16);
    } else {   // K rows 16..31 are pad -> register zeros
#pragma unroll
        for (int nt = 0; nt < 4; ++nt)
#pragma unroll
            for (int j = 0; j < 8; ++j) B4[nt][j] = (_Float16)0.0f;
    }
#pragma unroll
    for (int nt = 0; nt < 4; ++nt) {
        f32x4 C = b4v;
        C = __builtin_amdgcn_mfma_f32_16x16x32_f16(A4w, B4[nt], C, 0, 0, 0);
        *(f32x4*)(smem + 2560 + (nt*16 + n16) * 80 + q * 16) = C;
    }

    // ---- each lane reads its own p row ----
    float p[9];
    {
        const char* pr = smem + 2560 + lane * 80;
        *(f32x4*)&p[0] = *(const f32x4*)(pr);
        *(f32x4*)&p[4] = *(const f32x4*)(pr + 16);
        p[8] = *(const float*)(pr + 32);
    }

    // ---- heads ----
    const float K00 = __expf(p[0]), K01 = __expf(p[1]);
    const float K10 = __expf(p[2]), K11 = __expf(p[3]);

    const float sh_m0 = kLOW + (kHIGH - kLOW) * fast_sigmoid(p[4]);
    const float sh_m1 = kLOW + (kHIGH - kLOW) * fast_sigmoid(p[5]);
    const float sh_f0 = kLOW + (kHIGH - kLOW) * fast_sigmoid(p[6]);
    const float sh_f1 = kLOW + (kHIGH - kLOW) * fast_sigmoid(p[7]);
    const float V = __expf(p[8]);

    const float M0 = x[0], M1 = x[1], M2 = x[2];
    const float F0 = x[3], F1 = x[4], F2 = x[5];

    const float r0 = M0 * sh_m0, r1 = M1 * sh_m1, r2 = M2;
    const float c0 = F0 * sh_f0, c1 = F1 * sh_f1, c2 = F2;
    const float mum0_0 = M0 * (1.0f - sh_m0), mum0_1 = M1 * (1.0f - sh_m1);
    const float mu0f_0 = F0 * (1.0f - sh_f0), mu0f_1 = F1 * (1.0f - sh_f1);

    // ---- Sinkhorn in u/v form, gauge-fixed v2==1 for iters 1..9 ----
    const float rc2 = fast_rcp(c2);
    const float g0 = c0 * rc2, g1 = c1 * rc2;
    float v0 = 1.0f, v1 = 1.0f;
    float u0, u1, u2;
#pragma unroll
    for (int it = 0; it < 9; ++it) {
        const float s0 = fmaf(K00, v0, fmaf(K01, v1, 1.0f));
        const float s1 = fmaf(K10, v0, fmaf(K11, v1, 1.0f));
        const float s2 = v0 + v1 + 1.0f;
        u0 = r0 * fast_rcp(s0);
        u1 = r1 * fast_rcp(s1);
        u2 = r2 * fast_rcp(s2);
        const float t0 = fmaf(K00, u0, fmaf(K10, u1, u2));
        const float t1 = fmaf(K01, u0, fmaf(K11, u1, u2));
        const float t2 = u0 + u1 + u2;
        v0 = g0 * (t2 * fast_rcp(t0));
        v1 = g1 * (t2 * fast_rcp(t1));
    }
    float vf0, vf1, vf2;
    {
        const float s0 = fmaf(K00, v0, fmaf(K01, v1, 1.0f));
        const float s1 = fmaf(K10, v0, fmaf(K11, v1, 1.0f));
        const float s2 = v0 + v1 + 1.0f;
        u0 = r0 * fast_rcp(s0);
        u1 = r1 * fast_rcp(s1);
        u2 = r2 * fast_rcp(s2);
        const float t0 = fmaf(K00, u0, fmaf(K10, u1, u2));
        const float t1 = fmaf(K01, u0, fmaf(K11, u1, u2));
        const float t2 = u0 + u1 + u2;
        vf0 = c0 * fast_rcp(t0);
        vf1 = c1 * fast_rcp(t1);
        vf2 = c2 * fast_rcp(t2);
    }
    const float A00 = u0 * K00 * vf0, A01 = u0 * K01 * vf1, A02 = u0 * vf2;
    const float A10 = u1 * K10 * vf0, A11 = u1 * K11 * vf1, A12 = u1 * vf2;
    const float A20 = u2 * vf0,       A21 = u2 * vf1,       A22 = u2 * vf2;

    // ---- store ----
    if (row < B) {
        float4* o = (float4*)(out_mus + (size_t)row * 16);
        o[0] = make_float4(A00, A01, A02, mum0_0);
        o[1] = make_float4(A10, A11, A12, mum0_1);
        o[2] = make_float4(A20, A21, A22, 0.0f);
        o[3] = make_float4(mu0f_0, mu0f_1, 0.0f, 0.0f);
        out_V[row] = V;
    }
}

extern "C" void kernel_launch(void* const* d_in, const int* in_sizes, int n_in,
                              void* d_out, int out_size, void* d_ws, size_t ws_size,
                              hipStream_t stream) {
    const float* margins = (const float*)d_in[0];
    const float* W1 = (const float*)d_in[1];
    const float* b1 = (const float*)d_in[2];
    const float* W2 = (const float*)d_in[3];
    const float* b2 = (const float*)d_in[4];
    const float* W3 = (const float*)d_in[5];
    const float* b3 = (const float*)d_in[6];
    const float* W4 = (const float*)d_in[7];
    const float* b4 = (const float*)d_in[8];

    const int B = in_sizes[0] / 6;
    float* out_mus = (float*)d_out;
    float* out_V   = out_mus + (size_t)B * 16;
    char*  ws      = (char*)d_ws;

    hipLaunchKernelGGL(prep_frags, dim3(1), dim3(256), 0, stream,
                       W1, b1, W2, b2, W3, b3, W4, b4, ws);

    dim3 block(256);
    dim3 grid((B + 255) / 256);
    hipLaunchKernelGGL(sinkhorn_mlp_mfma, grid, block, 0, stream,
                       margins, ws, out_mus, out_V, B);
}

// Round 5
// 214.133 us; speedup vs baseline: 1.2645x; 1.2645x over previous
//
#include <hip/hip_runtime.h>

typedef _Float16 f16x8 __attribute__((ext_vector_type(8)));
typedef _Float16 f16x4 __attribute__((ext_vector_type(4)));
typedef __fp16   fp16x2 __attribute__((ext_vector_type(2)));
typedef float    f32x4 __attribute__((ext_vector_type(4)));

static constexpr float kLOW  = 0.02f;
static constexpr float kHIGH = 0.98f;

__device__ __forceinline__ float fast_rcp(float v) {
    return __builtin_amdgcn_rcpf(v);  // v_rcp_f32, ~1e-7 rel err
}
__device__ __forceinline__ float fast_sigmoid(float v) {
    return fast_rcp(1.0f + __expf(-v));
}
// relu + packed f32->f16 (RTZ): 1 v_cvt_pkrtz_f16_f32 per 2 elems vs 3 insts
__device__ __forceinline__ unsigned int relu_pk(float a, float b) {
    fp16x2 r = __builtin_amdgcn_cvt_pkrtz(fmaxf(a, 0.0f), fmaxf(b, 0.0f));
    return __builtin_bit_cast(unsigned int, r);
}

// ---------------- workspace layout (bytes) ----------------
enum : int {
    WS_A1 = 0,        // [4 mt][64 lane] f16x8   W1^T frags (K=32 pad, q>0 zero)
    WS_A2 = 4096,     // [2 mt][2 kt][64] f16x8  W2^T frags
    WS_A3 = 8192,     // [64] f16x8              W3^T frag
    WS_A4 = 9216,     // [64] f16x8              W4^T frag (M=16 pad, K=32 pad)
    WS_B1 = 10240,    // [4 mt][64] f32x4        b1 per-lane C-in rows
    WS_B2 = 14336,    // [2 mt][64] f32x4
    WS_B3 = 16384,    // [64] f32x4
    WS_B4 = 17408,    // [64] f32x4 (rows >=9 zeroed)
    WS_TOTAL = 18432
};

__global__ __launch_bounds__(256) void prep_frags(
    const float* __restrict__ W1, const float* __restrict__ b1,
    const float* __restrict__ W2, const float* __restrict__ b2,
    const float* __restrict__ W3, const float* __restrict__ b3,
    const float* __restrict__ W4, const float* __restrict__ b4,
    char* __restrict__ ws)
{
    const int lane = threadIdx.x & 63;
    const int wid  = threadIdx.x >> 6;
    const int n16  = lane & 15;
    const int q    = lane >> 4;

    if (wid == 0) {
#pragma unroll
        for (int mt = 0; mt < 4; ++mt) {
            f16x8 a;
#pragma unroll
            for (int j = 0; j < 8; ++j) a[j] = (_Float16)0.0f;
            if (q == 0) {
#pragma unroll
                for (int j = 0; j < 6; ++j)
                    a[j] = (_Float16)W1[j * 64 + mt * 16 + n16];
            }
            ((f16x8*)(ws + WS_A1))[mt * 64 + lane] = a;
        }
#pragma unroll
        for (int mt = 0; mt < 4; ++mt)
            ((f32x4*)(ws + WS_B1))[mt * 64 + lane] = *(const f32x4*)(b1 + mt * 16 + q * 4);
    } else if (wid == 1) {
#pragma unroll
        for (int mt = 0; mt < 2; ++mt)
#pragma unroll
            for (int kt = 0; kt < 2; ++kt) {
                f16x8 a;
#pragma unroll
                for (int j = 0; j < 8; ++j)
                    a[j] = (_Float16)W2[(kt * 32 + q * 8 + j) * 32 + mt * 16 + n16];
                ((f16x8*)(ws + WS_A2))[(mt * 2 + kt) * 64 + lane] = a;
            }
    } else if (wid == 2) {
        f16x8 a3;
#pragma unroll
        for (int j = 0; j < 8; ++j)
            a3[j] = (_Float16)W3[(q * 8 + j) * 16 + n16];
        ((f16x8*)(ws + WS_A3))[lane] = a3;
        f16x8 a4;
#pragma unroll
        for (int j = 0; j < 8; ++j) {
            const int k = q * 8 + j;
            a4[j] = (k < 16 && n16 < 9) ? (_Float16)W4[k * 9 + n16] : (_Float16)0.0f;
        }
        ((f16x8*)(ws + WS_A4))[lane] = a4;
    } else {
#pragma unroll
        for (int mt = 0; mt < 2; ++mt)
            ((f32x4*)(ws + WS_B2))[mt * 64 + lane] = *(const f32x4*)(b2 + mt * 16 + q * 4);
        ((f32x4*)(ws + WS_B3))[lane] = *(const f32x4*)(b3 + q * 4);
        f32x4 bb;
#pragma unroll
        for (int r = 0; r < 4; ++r) {
            const int m = q * 4 + r;
            bb[r] = (m < 9) ? b4[m] : 0.0f;
        }
        ((f32x4*)(ws + WS_B4))[lane] = bb;
    }
}

// Per-wave LDS slice 8192 B. Regions (time-multiplexed; every hazard is
// read-to-regs-before-overwrite within the same wave, ordered by lgkmcnt):
//   x^T f16 rows @ 7168..8192 (aliases h1 rows 56..63; x fully consumed into
//     BX registers before any h1 write)
//   h1 f16 [b][128 B] swizzled (byte ^= (b&7)<<4) @ 0..8192
//   h2 f16 [b][32] stride  80 @ 0..5104
//   h3 f16 [b][16] stride  32 @ 0..2048
//   pbuf f32 [b][12+pad] stride 80 @ 2560..7664
//   out-stage f32 [b][16] stride 80 @ 2560..7680 (after p consumed)
// launch_bounds back to (256,4): R4's (256,5) never yielded the 5th block
// (Occupancy stayed 37.8%) and only squeezed the register budget.
__global__ __launch_bounds__(256, 4) void sinkhorn_mlp_mfma(
    const float* __restrict__ margins, const char* __restrict__ ws,
    float* __restrict__ out_mus, float* __restrict__ out_V, int B)
{
    __shared__ __align__(16) char smem_all[4 * 8192];
    const int lane = threadIdx.x & 63;
    const int wid  = threadIdx.x >> 6;
    char* smem = smem_all + wid * 8192;

    const int n16 = lane & 15;   // MFMA tile row/col index
    const int q   = lane >> 4;   // quad 0..3

    const int wbase = blockIdx.x * 256 + wid * 64;   // first row of this wave
    const int row   = wbase + lane;
    const int rowC  = row < B ? row : (B - 1);

    // ---- load input row (f32 kept for sinkhorn margins) ----
    float x[6];
    {
        const float2* mp = (const float2*)(margins + (size_t)rowC * 6);
        const float2 a = mp[0], b = mp[1], c = mp[2];
        x[0] = a.x; x[1] = a.y; x[2] = b.x; x[3] = b.y; x[4] = c.x; x[5] = c.y;
    }

    // ---- stage x^T rows as f16 (k=0..5 data, 6..7 zero) ----
    {
        f16x8 xr;
#pragma unroll
        for (int j = 0; j < 8; ++j) xr[j] = (_Float16)0.0f;
#pragma unroll
        for (int i = 0; i < 6; ++i) xr[i] = (_Float16)x[i];
        *(f16x8*)(smem + 7168 + lane * 16) = xr;
    }

    // ---- fragments: coalesced b128 loads from prepacked ws ----
    f16x8 A1[4], A2w[2][2], A3w, A4w;
#pragma unroll
    for (int mt = 0; mt < 4; ++mt) A1[mt] = ((const f16x8*)(ws + WS_A1))[mt * 64 + lane];
#pragma unroll
    for (int mt = 0; mt < 2; ++mt)
#pragma unroll
        for (int kt = 0; kt < 2; ++kt)
            A2w[mt][kt] = ((const f16x8*)(ws + WS_A2))[(mt * 2 + kt) * 64 + lane];
    A3w = ((const f16x8*)(ws + WS_A3))[lane];
    A4w = ((const f16x8*)(ws + WS_A4))[lane];

    f32x4 b1v[4], b2v[2], b3v, b4v;
#pragma unroll
    for (int mt = 0; mt < 4; ++mt) b1v[mt] = ((const f32x4*)(ws + WS_B1))[mt * 64 + lane];
#pragma unroll
    for (int mt = 0; mt < 2; ++mt) b2v[mt] = ((const f32x4*)(ws + WS_B2))[mt * 64 + lane];
    b3v = ((const f32x4*)(ws + WS_B3))[lane];
    b4v = ((const f32x4*)(ws + WS_B4))[lane];

    // ---- layer 1: h1^T = W1^T x^T  (M=64, N=64, K=32 pad) ----
    // B-frag rows k=8..31 are zero: q>0 lanes take register zeros (no LDS).
    f16x8 BX[4];
    if (q == 0) {
#pragma unroll
        for (int nt = 0; nt < 4; ++nt)
            BX[nt] = *(const f16x8*)(smem + 7168 + (nt * 16 + n16) * 16);
    } else {
#pragma unroll
        for (int nt = 0; nt < 4; ++nt)
#pragma unroll
            for (int j = 0; j < 8; ++j) BX[nt][j] = (_Float16)0.0f;
    }
#pragma unroll
    for (int mt = 0; mt < 4; ++mt) {
#pragma unroll
        for (int nt = 0; nt < 4; ++nt) {
            f32x4 C = b1v[mt];
            C = __builtin_amdgcn_mfma_f32_16x16x32_f16(A1[mt], BX[nt], C, 0, 0, 0);
            uint2 hv;
            hv.x = relu_pk(C[0], C[1]);
            hv.y = relu_pk(C[2], C[3]);
            const int r = nt * 16 + n16;                       // batch row
            const int col = (mt * 32 + q * 8) ^ ((r & 7) << 4); // XOR swizzle
            *(uint2*)(smem + r * 128 + col) = hv;
        }
    }

    // ---- layer 2: h2^T = W2^T h1^T  (M=32, N=64, K=64) ----
    f16x8 H1f[4][2];
#pragma unroll
    for (int nt = 0; nt < 4; ++nt) {
        const int r = nt * 16 + n16;
#pragma unroll
        for (int kt = 0; kt < 2; ++kt) {
            const int col = (kt * 64 + q * 16) ^ ((r & 7) << 4);
            H1f[nt][kt] = *(const f16x8*)(smem + r * 128 + col);
        }
    }
#pragma unroll
    for (int mt = 0; mt < 2; ++mt) {
#pragma unroll
        for (int nt = 0; nt < 4; ++nt) {
            f32x4 C = b2v[mt];
            C = __builtin_amdgcn_mfma_f32_16x16x32_f16(A2w[mt][0], H1f[nt][0], C, 0, 0, 0);
            C = __builtin_amdgcn_mfma_f32_16x16x32_f16(A2w[mt][1], H1f[nt][1], C, 0, 0, 0);
            uint2 hv;
            hv.x = relu_pk(C[0], C[1]);
            hv.y = relu_pk(C[2], C[3]);
            *(uint2*)(smem + (nt*16 + n16) * 80 + mt*32 + q*8) = hv;
        }
    }

    // ---- layer 3: h3^T = W3^T h2^T  (M=16, N=64, K=32), RNE for accuracy ----
    f16x8 H2f[4];
#pragma unroll
    for (int nt = 0; nt < 4; ++nt)
        H2f[nt] = *(const f16x8*)(smem + (nt*16 + n16) * 80 + q*16);
#pragma unroll
    for (int nt = 0; nt < 4; ++nt) {
        f32x4 C = b3v;
        C = __builtin_amdgcn_mfma_f32_16x16x32_f16(A3w, H2f[nt], C, 0, 0, 0);
        f16x4 hv;
#pragma unroll
        for (int r = 0; r < 4; ++r) hv[r] = (_Float16)fmaxf(C[r], 0.0f);
        *(f16x4*)(smem + (nt*16 + n16) * 32 + q*8) = hv;
    }

    // ---- layer 4 on MFMA: p^T = W4^T h3^T (M=16 pad(9), N=64, K=32 pad(16)) ----
    f16x8 B4[4];
    if (q < 2) {
#pragma unroll
        for (int nt = 0; nt < 4; ++nt)
            B4[nt] = *(const f16x8*)(smem + (nt*16 + n16) * 32 + q * 16);
    } else {   // K rows 16..31 are pad -> register zeros
#pragma unroll
        for (int nt = 0; nt < 4; ++nt)
#pragma unroll
            for (int j = 0; j < 8; ++j) B4[nt][j] = (_Float16)0.0f;
    }
#pragma unroll
    for (int nt = 0; nt < 4; ++nt) {
        f32x4 C = b4v;
        C = __builtin_amdgcn_mfma_f32_16x16x32_f16(A4w, B4[nt], C, 0, 0, 0);
        *(f32x4*)(smem + 2560 + (nt*16 + n16) * 80 + q * 16) = C;
    }

    // ---- each lane reads its own p row ----
    float p[9];
    {
        const char* pr = smem + 2560 + lane * 80;
        *(f32x4*)&p[0] = *(const f32x4*)(pr);
        *(f32x4*)&p[4] = *(const f32x4*)(pr + 16);
        p[8] = *(const float*)(pr + 32);
    }

    // ---- heads ----
    const float K00 = __expf(p[0]), K01 = __expf(p[1]);
    const float K10 = __expf(p[2]), K11 = __expf(p[3]);

    const float sh_m0 = kLOW + (kHIGH - kLOW) * fast_sigmoid(p[4]);
    const float sh_m1 = kLOW + (kHIGH - kLOW) * fast_sigmoid(p[5]);
    const float sh_f0 = kLOW + (kHIGH - kLOW) * fast_sigmoid(p[6]);
    const float sh_f1 = kLOW + (kHIGH - kLOW) * fast_sigmoid(p[7]);
    const float V = __expf(p[8]);

    const float M0 = x[0], M1 = x[1], M2 = x[2];
    const float F0 = x[3], F1 = x[4], F2 = x[5];

    const float r0 = M0 * sh_m0, r1 = M1 * sh_m1, r2 = M2;
    const float c0 = F0 * sh_f0, c1 = F1 * sh_f1, c2 = F2;
    const float mum0_0 = M0 * (1.0f - sh_m0), mum0_1 = M1 * (1.0f - sh_m1);
    const float mu0f_0 = F0 * (1.0f - sh_f0), mu0f_1 = F1 * (1.0f - sh_f1);

    // ---- Sinkhorn in u/v form, gauge-fixed v2==1 for iters 1..9 ----
    const float rc2 = fast_rcp(c2);
    const float g0 = c0 * rc2, g1 = c1 * rc2;
    float v0 = 1.0f, v1 = 1.0f;
    float u0, u1, u2;
#pragma unroll
    for (int it = 0; it < 9; ++it) {
        const float s0 = fmaf(K00, v0, fmaf(K01, v1, 1.0f));
        const float s1 = fmaf(K10, v0, fmaf(K11, v1, 1.0f));
        const float s2 = v0 + v1 + 1.0f;
        u0 = r0 * fast_rcp(s0);
        u1 = r1 * fast_rcp(s1);
        u2 = r2 * fast_rcp(s2);
        const float t0 = fmaf(K00, u0, fmaf(K10, u1, u2));
        const float t1 = fmaf(K01, u0, fmaf(K11, u1, u2));
        const float t2 = u0 + u1 + u2;
        v0 = g0 * (t2 * fast_rcp(t0));
        v1 = g1 * (t2 * fast_rcp(t1));
    }
    float vf0, vf1, vf2;
    {
        const float s0 = fmaf(K00, v0, fmaf(K01, v1, 1.0f));
        const float s1 = fmaf(K10, v0, fmaf(K11, v1, 1.0f));
        const float s2 = v0 + v1 + 1.0f;
        u0 = r0 * fast_rcp(s0);
        u1 = r1 * fast_rcp(s1);
        u2 = r2 * fast_rcp(s2);
        const float t0 = fmaf(K00, u0, fmaf(K10, u1, u2));
        const float t1 = fmaf(K01, u0, fmaf(K11, u1, u2));
        const float t2 = u0 + u1 + u2;
        vf0 = c0 * fast_rcp(t0);
        vf1 = c1 * fast_rcp(t1);
        vf2 = c2 * fast_rcp(t2);
    }
    const float A00 = u0 * K00 * vf0, A01 = u0 * K01 * vf1, A02 = u0 * vf2;
    const float A10 = u1 * K10 * vf0, A11 = u1 * K11 * vf1, A12 = u1 * vf2;
    const float A20 = u2 * vf0,       A21 = u2 * vf1,       A22 = u2 * vf2;

    // ---- store: transpose through LDS -> fully coalesced full-line writes ----
    // R4 lesson: direct per-row float4 stores (16 B/lane at stride 64 B) caused
    // partial-cache-line RMW amplification (WRITE 311 MB vs 142 MB of output,
    // FETCH +53 MB of output read-back). Stage the wave's 64x64 B tile in LDS
    // (stride 80 = conflict-minimal), then each store instruction writes 1 KiB
    // contiguous: every 128-B line is produced by a single instruction.
    {
        char* ob = smem + 2560;   // p-buffer already consumed into registers
        f32x4* s = (f32x4*)(ob + lane * 80);
        s[0] = f32x4{A00, A01, A02, mum0_0};
        s[1] = f32x4{A10, A11, A12, mum0_1};
        s[2] = f32x4{A20, A21, A22, 0.0f};
        s[3] = f32x4{mu0f_0, mu0f_1, 0.0f, 0.0f};

        if (wbase + 64 <= B) {
            float* og = out_mus + (size_t)wbase * 16;
#pragma unroll
            for (int k = 0; k < 4; ++k) {
                const int g = k * 64 + lane;          // float4 index in wave tile
                const int r = g >> 2, c = g & 3;
                f32x4 v = *(const f32x4*)(ob + r * 80 + c * 16);
                *(f32x4*)(og + (size_t)g * 4) = v;
            }
            out_V[wbase + lane] = V;
        } else if (row < B) {                         // tail wave (B not /64)
            float* og = out_mus + (size_t)row * 16;
            const char* sr = ob + lane * 80;
#pragma unroll
            for (int c = 0; c < 4; ++c)
                *(f32x4*)(og + c * 4) = *(const f32x4*)(sr + c * 16);
            out_V[row] = V;
        }
    }
}

extern "C" void kernel_launch(void* const* d_in, const int* in_sizes, int n_in,
                              void* d_out, int out_size, void* d_ws, size_t ws_size,
                              hipStream_t stream) {
    const float* margins = (const float*)d_in[0];
    const float* W1 = (const float*)d_in[1];
    const float* b1 = (const float*)d_in[2];
    const float* W2 = (const float*)d_in[3];
    const float* b2 = (const float*)d_in[4];
    const float* W3 = (const float*)d_in[5];
    const float* b3 = (const float*)d_in[6];
    const float* W4 = (const float*)d_in[7];
    const float* b4 = (const float*)d_in[8];

    const int B = in_sizes[0] / 6;
    float* out_mus = (float*)d_out;
    float* out_V   = out_mus + (size_t)B * 16;
    char*  ws      = (char*)d_ws;

    hipLaunchKernelGGL(prep_frags, dim3(1), dim3(256), 0, stream,
                       W1, b1, W2, b2, W3, b3, W4, b4, ws);

    dim3 block(256);
    dim3 grid((B + 255) / 256);
    hipLaunchKernelGGL(sinkhorn_mlp_mfma, grid, block, 0, stream,
                       margins, ws, out_mus, out_V, B);
}